// Round 8
// baseline (157.223 us; speedup 1.0000x reference)
//
#include <hip/hip_runtime.h>
#include <stdint.h>

typedef unsigned short u16;
typedef __attribute__((ext_vector_type(8))) short   bf16x8;
typedef __attribute__((ext_vector_type(4))) float   f32x4;
typedef __attribute__((ext_vector_type(4))) u16     u16x4;
typedef __attribute__((ext_vector_type(8))) u16     u16x8;

#define NN 2048      // nodes
#define BB 64        // batch
#define DD 64        // d_in = d_out
#define XSTRIDE (NN*DD)   // per-batch stride in x/out = 131072

__device__ __forceinline__ float bf2f(u16 u) {
    union { unsigned int i; float f; } v; v.i = ((unsigned int)u) << 16; return v.f;
}
__device__ __forceinline__ u16 f2bf(float f) {   // round-to-nearest-even
    union { float f; unsigned int i; } v; v.f = f;
    unsigned int u = v.i;
    return (u16)((u + 0x7fffu + ((u >> 16) & 1u)) >> 16);
}

typedef __attribute__((address_space(3))) unsigned int lds_u32_t;
typedef const __attribute__((address_space(1))) unsigned int g_u32_t;
__device__ __forceinline__ void gload_lds16(const void* g, void* l) {
    __builtin_amdgcn_global_load_lds((g_u32_t*)(uintptr_t)g, (lds_u32_t*)(uintptr_t)l, 16, 0, 0);
}

// ---- 1. LayerNorm over E=16 -> ne [2048][16] f32  +  neb [2048][32] bf16 ----
__global__ __launch_bounds__(256) void k_ln(const float* __restrict__ nodee,
                                            const float* __restrict__ timee,
                                            const float* __restrict__ gamma,
                                            const float* __restrict__ beta,
                                            float* __restrict__ ne,
                                            u16* __restrict__ neb) {
    int n = blockIdx.x * 256 + threadIdx.x;   // 8*256 = 2048
    float v[16]; float mu = 0.f;
    const float4* p = (const float4*)(nodee + (long)n * 16);
#pragma unroll
    for (int i = 0; i < 4; i++) {
        float4 q = p[i];
        v[i*4+0]=q.x; v[i*4+1]=q.y; v[i*4+2]=q.z; v[i*4+3]=q.w;
    }
#pragma unroll
    for (int e = 0; e < 16; e++) { v[e] += timee[e]; mu += v[e]; }
    mu *= (1.f/16.f);
    float var = 0.f;
#pragma unroll
    for (int e = 0; e < 16; e++) { float d = v[e]-mu; var += d*d; }
    var *= (1.f/16.f);
    float rs = rsqrtf(var + 1e-12f);
    float4* o = (float4*)(ne + (long)n * 16);
    u16x8 nb[2];
#pragma unroll
    for (int i = 0; i < 4; i++) {
        float4 q;
        q.x = (v[i*4+0]-mu)*rs*gamma[i*4+0] + beta[i*4+0];
        q.y = (v[i*4+1]-mu)*rs*gamma[i*4+1] + beta[i*4+1];
        q.z = (v[i*4+2]-mu)*rs*gamma[i*4+2] + beta[i*4+2];
        q.w = (v[i*4+3]-mu)*rs*gamma[i*4+3] + beta[i*4+3];
        o[i] = q;
        nb[i>>1][(i&1)*4+0] = f2bf(q.x); nb[i>>1][(i&1)*4+1] = f2bf(q.y);
        nb[i>>1][(i&1)*4+2] = f2bf(q.z); nb[i>>1][(i&1)*4+3] = f2bf(q.w);
    }
    u16x8 z;
#pragma unroll
    for (int j = 0; j < 8; j++) z[j] = 0;
    u16x8* ob = (u16x8*)&neb[(long)n * 32];
    ob[0] = nb[0]; ob[1] = nb[1]; ob[2] = z; ob[3] = z;
}

// ---- 2. wpP[j=o*192+ki][e(pad32)] = bf16(wp[e][ki][o])  [12288][32] ---------
__global__ __launch_bounds__(256) void k_wperm(const float* __restrict__ wp,
                                               u16* __restrict__ wpP) {
    int j = blockIdx.x * 256 + threadIdx.x;   // 48 blocks
    int o = j / 192, ki = j - o * 192;
    int src = ki * 64 + o;
    u16x8 ov[4];
#pragma unroll
    for (int e = 0; e < 16; e++) ov[e>>3][e&7] = f2bf(wp[(long)e*12288 + src]);
#pragma unroll
    for (int e = 0; e < 8; e++) { ov[2][e] = 0; ov[3][e] = 0; }
    u16x8* dst = (u16x8*)&wpP[(long)j * 32];
    dst[0]=ov[0]; dst[1]=ov[1]; dst[2]=ov[2]; dst[3]=ov[3];
}

// ---------------- 3. S = softmax(ne @ ne^T) row-wise -> bf16 [2048][2048] ----
__global__ __launch_bounds__(256) void k_softmax(const float* __restrict__ ne,
                                                 u16* __restrict__ S) {
    __shared__ float row[2048];
    __shared__ float red[8];
    int n = blockIdx.x, t = threadIdx.x;
    int wave = t >> 6, lane = t & 63;
    f32x4 nev[4];
#pragma unroll
    for (int i = 0; i < 4; i++) nev[i] = *(const f32x4*)&ne[n*16 + i*4];
    float lmax = -1e30f;
    for (int m = t; m < 2048; m += 256) {
        const f32x4* p = (const f32x4*)&ne[m*16];
        f32x4 d4 = nev[0]*p[0] + nev[1]*p[1] + nev[2]*p[2] + nev[3]*p[3];
        float d = d4[0]+d4[1]+d4[2]+d4[3];
        row[m] = d;
        lmax = fmaxf(lmax, d);
    }
#pragma unroll
    for (int off = 32; off > 0; off >>= 1) lmax = fmaxf(lmax, __shfl_xor(lmax, off));
    if (lane == 0) red[wave] = lmax;
    __syncthreads();
    float gmax = fmaxf(fmaxf(red[0], red[1]), fmaxf(red[2], red[3]));
    float lsum = 0.f;
    for (int m = t; m < 2048; m += 256) {
        float ev = __expf(row[m] - gmax);
        row[m] = ev;
        lsum += ev;
    }
#pragma unroll
    for (int off = 32; off > 0; off >>= 1) lsum += __shfl_xor(lsum, off);
    __syncthreads();                 // everyone done reading red for gmax
    if (lane == 0) red[wave] = lsum;
    __syncthreads();
    float inv = 1.f / (red[0]+red[1]+red[2]+red[3]);
    for (int m = t; m < 2048; m += 256)
        S[(long)n*2048 + m] = f2bf(row[m] * inv);
}

// ---------------- 4. Xpt[j=(b,c)][m] = bf16(x[b][m][c])  [4096][2048] -------
__global__ __launch_bounds__(256) void k_permute(const float* __restrict__ x,
                                                 u16* __restrict__ Xpt) {
    __shared__ u16 T[64][72];
    int bid = blockIdx.x;             // 64 b * 32 m-tiles
    int b = bid >> 5, m0 = (bid & 31) * 64;
    int t = threadIdx.x;
#pragma unroll
    for (int it = 0; it < 4; it++) {
        int fi = it*256 + t;
        int row = fi >> 4, c4 = (fi & 15) * 4;   // row = local m
        float4 v = *(const float4*)&x[(long)b*XSTRIDE + (m0+row)*64 + c4];
        T[c4+0][row] = f2bf(v.x); T[c4+1][row] = f2bf(v.y);
        T[c4+2][row] = f2bf(v.z); T[c4+3][row] = f2bf(v.w);
    }
    __syncthreads();
#pragma unroll
    for (int it = 0; it < 2; it++) {
        int ch = it*256 + t;
        int c = ch >> 3, m8 = (ch & 7) * 8;
        u16x8 v = *(const u16x8*)&T[c][m8];
        *(u16x8*)&Xpt[(long)(b*64 + c)*2048 + m0 + m8] = v;
    }
}

// ---- 5a. small-K GEMM (weight pool): C = A * Bt^T, 128x128 tile, K small ----
__global__ __launch_bounds__(256) void k_gemm_bt(const u16* __restrict__ A,
                                                 const u16* __restrict__ Bt,
                                                 u16* __restrict__ C,
                                                 int M, int Ncols, int K) {
    __shared__ __align__(16) u16 As[128*32];
    __shared__ __align__(16) u16 Bs[128*32];
    const int t = threadIdx.x;
    const int wave = t >> 6, lane = t & 63;
    const int l15 = lane & 15, lhi = lane >> 4;
    const int m0 = blockIdx.y * 128;
    const int n0 = blockIdx.x * 128;
    const int wr = wave >> 1, wc = wave & 1;
    f32x4 acc[4][4] = {};
    const int srow = t >> 2;
    const int sk = (t & 3) * 8;
    const u16* gA = A + (long)(m0 + srow) * K + sk;
    const u16* gB = Bt + (long)(n0 + srow) * K + sk;
    const long half = (long)64 * K;
    u16* lA = As + wave * 512;   // elems; wave-uniform base, HW adds lane*16B
    u16* lB = Bs + wave * 512;
    const int aoff = (wr*64 + l15)*32 + lhi*8;
    const int boff = (wc*64 + l15)*32 + lhi*8;
    for (int k0 = 0; k0 < K; k0 += 32) {
        gload_lds16(gA + k0,        lA);
        gload_lds16(gA + k0 + half, lA + 2048);
        gload_lds16(gB + k0,        lB);
        gload_lds16(gB + k0 + half, lB + 2048);
        __syncthreads();
        bf16x8 af[4], bv[4];
#pragma unroll
        for (int m = 0; m < 4; m++) af[m] = *(const bf16x8*)&As[aoff + m*512];
#pragma unroll
        for (int q = 0; q < 4; q++) bv[q] = *(const bf16x8*)&Bs[boff + q*512];
#pragma unroll
        for (int m = 0; m < 4; m++)
#pragma unroll
            for (int q = 0; q < 4; q++)
                acc[m][q] = __builtin_amdgcn_mfma_f32_16x16x32_bf16(af[m], bv[q], acc[m][q], 0, 0, 0);
        __syncthreads();
    }
#pragma unroll
    for (int m = 0; m < 4; m++) {
        int row = m0 + wr*64 + m*16 + lhi*4;
#pragma unroll
        for (int q = 0; q < 4; q++) {
            int col = n0 + wc*64 + q*16 + l15;
#pragma unroll
            for (int r = 0; r < 4; r++)
                C[(long)(row + r) * Ncols + col] = f2bf(acc[m][q][r]);
        }
    }
}

// ---- 5b. big GEMM: C[M][Ncols] = A[M][K]*Bt[Ncols][K]^T, optional Ct=C^T ----
// BM=128, BN=256, BK=64. 512 thr = 8 waves = 4 spatial (2Mx2N) x 2 K-split.
// Each wave owns a 64x128 output tile (12 ds_read_b128 per 32 MFMA, -25% LDS
// traffic vs 64x64) and computes only its kstep (kw) of each K-tile; kw-pairs
// reduce via LDS f32 at the end. R3-proven loop: triple-buffered 144KB LDS,
// 2-tile-ahead prefetch, ONE counted vmcnt(6) + ONE barrier per K-tile (T3+T4),
// XOR-swizzled LDS both-sides (T2), setprio (T5), XCD swizzle (T1).
__global__ __launch_bounds__(512, 2) void k_gemm_big(const u16* __restrict__ A,
                                                     const u16* __restrict__ Bt,
                                                     u16* __restrict__ C,
                                                     u16* __restrict__ Ct,
                                                     int M, int Ncols, int K) {
    __shared__ __align__(16) u16 LB[73728];   // 144 KB: A 3x8192 @0, B 3x16384 @24576
    const int t = threadIdx.x;
    const int wave = t >> 6, lane = t & 63;
    const int l15 = lane & 15, lhi = lane >> 4;
    // T1: XCD swizzle (nwg = 256, divisible by 8)
    const int nwg = gridDim.x * gridDim.y;
    const int wgid = blockIdx.y * gridDim.x + blockIdx.x;
    const int swz = (wgid & 7) * (nwg >> 3) + (wgid >> 3);
    const int by = swz / gridDim.x, bx = swz - by * gridDim.x;
    const int m0 = by * 128, n0 = bx * 256;
    const int kwv = wave & 1;            // K-split half
    const int ws  = wave >> 1;           // spatial 0..3
    const int wr = ws >> 1, wc = ws & 1; // 2M x 2N spatial grid, 64x128 each
    const int NT = K >> 6;
    f32x4 acc[4][8] = {};

    // staging: chunk c = pass*512 + t; row = pass*64 + (t>>3), slot = t&7.
    // inverse swizzle: global k8-chunk = slot ^ (row&7); pass*64 == 0 mod 8.
    const int srow = t >> 3;
    const int sswz = ((t & 7) ^ (srow & 7)) * 8;
    const u16* gA0 = A  + (long)(m0 + srow) * K + sswz;
    const u16* gB0 = Bt + (long)(n0 + srow) * K + sswz;
    const long rP = (long)64 * K;   // 64-row advance per staging pass
    const int ldsW = wave * 512;    // wave-uniform dest base (elems); HW adds lane*16B

    int curA = 0,     nxtA = 8192,  tgtA = 16384;
    int curB = 24576, nxtB = 40960, tgtB = 57344;

    // prologue: tile 0 -> cur, tile 1 -> nxt (6 loads per thread per tile)
    gload_lds16(gA0,           &LB[curA + 0*4096 + ldsW]);
    gload_lds16(gA0 + rP,      &LB[curA + 1*4096 + ldsW]);
#pragma unroll
    for (int r = 0; r < 4; r++) gload_lds16(gB0 + r*rP,      &LB[curB + r*4096 + ldsW]);
    gload_lds16(gA0 + 64,      &LB[nxtA + 0*4096 + ldsW]);
    gload_lds16(gA0 + rP + 64, &LB[nxtA + 1*4096 + ldsW]);
#pragma unroll
    for (int r = 0; r < 4; r++) gload_lds16(gB0 + r*rP + 64, &LB[nxtB + r*4096 + ldsW]);
    asm volatile("s_waitcnt vmcnt(6)" ::: "memory");   // tile 0 resident
    __builtin_amdgcn_s_barrier();
    asm volatile("" ::: "memory");

    // read-side addressing: row has 8 slots of 8 elems; logical slot g (=kw*4+lhi)
    // lives at LDS slot g ^ (row&7); m*16 / q*16 don't change row&7.
    const int rsw = l15 & 7;
    const int swk = ((kwv*4 + lhi) ^ rsw) * 8;   // this wave's kstep slots
    const int abase = (wr*64  + l15) * 64;
    const int bbase = (wc*128 + l15) * 64;

#pragma unroll 1
    for (int tt = 0; tt < NT; tt++) {
        const bool stg = (tt + 2 < NT);
        const long ko2 = (long)((tt + 2) << 6);
        bf16x8 af[4], bv[8];
#pragma unroll
        for (int m = 0; m < 4; m++) af[m] = *(const bf16x8*)&LB[curA + abase + m*1024 + swk];
#pragma unroll
        for (int q = 0; q < 8; q++) bv[q] = *(const bf16x8*)&LB[curB + bbase + q*1024 + swk];
        if (stg) {
            gload_lds16(gA0 + ko2,        &LB[tgtA + 0*4096 + ldsW]);
            gload_lds16(gA0 + rP + ko2,   &LB[tgtA + 1*4096 + ldsW]);
            gload_lds16(gB0 + ko2,        &LB[tgtB + 0*4096 + ldsW]);
            gload_lds16(gB0 + 1*rP + ko2, &LB[tgtB + 1*4096 + ldsW]);
            gload_lds16(gB0 + 2*rP + ko2, &LB[tgtB + 2*4096 + ldsW]);
            gload_lds16(gB0 + 3*rP + ko2, &LB[tgtB + 3*4096 + ldsW]);
        }
        __builtin_amdgcn_s_setprio(1);
#pragma unroll
        for (int m = 0; m < 4; m++)
#pragma unroll
            for (int q = 0; q < 8; q++)
                acc[m][q] = __builtin_amdgcn_mfma_f32_16x16x32_bf16(af[m], bv[q], acc[m][q], 0, 0, 0);
        __builtin_amdgcn_s_setprio(0);
        // ---------- end of tile: counted wait + raw barrier ----------
        asm volatile("" ::: "memory");
        if (stg)                asm volatile("s_waitcnt vmcnt(6)" ::: "memory");
        else if (tt + 1 < NT)   asm volatile("s_waitcnt vmcnt(0)" ::: "memory");
        if (tt + 1 < NT) {
            __builtin_amdgcn_s_barrier();
            asm volatile("" ::: "memory");
        }
        int ta = curA; curA = nxtA; nxtA = tgtA; tgtA = ta;
        int tb = curB; curB = nxtB; nxtB = tgtB; tgtB = tb;
    }

    // ---- K-split reduce: kw=1 waves dump acc to LDS, kw=0 waves add ----
    float* LBf = (float*)LB;
    __syncthreads();   // all K-loop LDS reads done
    if (kwv == 1) {
        const int base = ws*8192 + lane*4;
#pragma unroll
        for (int m = 0; m < 4; m++)
#pragma unroll
            for (int q = 0; q < 8; q++)
                *(f32x4*)&LBf[base + (m*8 + q)*256] = acc[m][q];
    }
    __syncthreads();
    if (kwv == 0) {
        const int base = ws*8192 + lane*4;
#pragma unroll
        for (int m = 0; m < 4; m++)
#pragma unroll
            for (int q = 0; q < 8; q++) {
                f32x4 p = *(const f32x4*)&LBf[base + (m*8 + q)*256];
                acc[m][q] += p;
            }
        // normal C write
#pragma unroll
        for (int m = 0; m < 4; m++) {
            int row = m0 + wr*64 + m*16 + lhi*4;
#pragma unroll
            for (int q = 0; q < 8; q++) {
                int col = n0 + wc*128 + q*16 + l15;
#pragma unroll
                for (int r = 0; r < 4; r++)
                    C[(long)(row + r) * Ncols + col] = f2bf(acc[m][q][r]);
            }
        }
    }
    // optional transposed write via LDS tile [256 col][128 row, stride 144]
    if (Ct != nullptr) {
        __syncthreads();   // reduce-area reads done before reuse
        if (kwv == 0) {
#pragma unroll
            for (int m = 0; m < 4; m++) {
                int rowb = wr*64 + m*16 + lhi*4;
#pragma unroll
                for (int q = 0; q < 8; q++) {
                    int col = wc*128 + q*16 + l15;
                    u16x4 p;
                    p[0]=f2bf(acc[m][q][0]); p[1]=f2bf(acc[m][q][1]);
                    p[2]=f2bf(acc[m][q][2]); p[3]=f2bf(acc[m][q][3]);
                    *(u16x4*)&LB[col*144 + rowb] = p;
                }
            }
        }
        __syncthreads();
        const int j = t >> 1, ch0 = (t & 1) * 64;
#pragma unroll
        for (int p = 0; p < 8; p++) {
            u16x8 v = *(const u16x8*)&LB[j*144 + ch0 + p*8];
            *(u16x8*)&Ct[(long)(n0 + j)*M + m0 + ch0 + p*8] = v;
        }
    }
}

// ---------------- 7. final: out[b][n][o] = sum_ki xg[b][ki]*W_n[ki][o]+bias --
__global__ __launch_bounds__(256) void k_final(const float* __restrict__ x,
                                               const u16* __restrict__ Y1,
                                               const u16* __restrict__ Y2,
                                               const u16* __restrict__ Wt,
                                               const float* __restrict__ ne,
                                               const float* __restrict__ bp,
                                               float* __restrict__ out) {
    __shared__ __align__(16) u16 Al[64*200];
    __shared__ __align__(16) u16 Wl[64*200];
    __shared__ float biasl[64];
    int n = blockIdx.x;
    int t = threadIdx.x;
    int wave = t >> 6, lane = t & 63;
    int l15 = lane & 15, lhi = lane >> 4;
    // W_n^T: global [o][ki] rows of 192 (192%8==0 so 8-chunks never cross rows)
#pragma unroll
    for (int it = 0; it < 6; it++) {
        int ch = it*256 + t;
        int o = ch / 24, kl = (ch % 24) * 8;
        u16x8 v = *(const u16x8*)&Wt[(long)n*12288 + ch*8];
        *(u16x8*)&Wl[o*200 + kl] = v;
    }
    // k=0 : x  (save f32 for k=2)
    float xs[16];
#pragma unroll
    for (int it = 0; it < 4; it++) {
        int fi = it*256 + t;
        int b = fi >> 4, i4 = (fi & 15) * 4;
        float4 v = *(const float4*)&x[(long)b*XSTRIDE + n*64 + i4];
        xs[it*4+0]=v.x; xs[it*4+1]=v.y; xs[it*4+2]=v.z; xs[it*4+3]=v.w;
        u16x4 p; p[0]=f2bf(v.x); p[1]=f2bf(v.y); p[2]=f2bf(v.z); p[3]=f2bf(v.w);
        *(u16x4*)&Al[b*200 + i4] = p;
    }
    // k=1 : Y1 row n
#pragma unroll
    for (int it = 0; it < 2; it++) {
        int ch = it*256 + t;
        int b = ch >> 3, i8 = (ch & 7)*8;
        u16x8 v = *(const u16x8*)&Y1[(long)n*4096 + ch*8];
        *(u16x8*)&Al[b*200 + 64 + i8] = v;
    }
    // k=2 : 2*Y2 - x
#pragma unroll
    for (int it = 0; it < 4; it++) {
        int fi = it*256 + t;
        int b = fi >> 4, i4 = (fi & 15)*4;
        u16x4 y = *(const u16x4*)&Y2[(long)n*4096 + fi*4];
        u16x4 p;
#pragma unroll
        for (int j = 0; j < 4; j++) p[j] = f2bf(2.f*bf2f(y[j]) - xs[it*4+j]);
        *(u16x4*)&Al[b*200 + 128 + i4] = p;
    }
    if (t < 64) {
        float s = 0.f;
#pragma unroll
        for (int e = 0; e < 16; e++) s += ne[n*16+e] * bp[e*64 + t];
        biasl[t] = s;
    }
    __syncthreads();
    f32x4 acc[4] = {};
#pragma unroll
    for (int kk = 0; kk < 6; kk++) {
        bf16x8 bv = *(const bf16x8*)&Wl[(wave*16 + l15)*200 + kk*32 + lhi*8];
#pragma unroll
        for (int m = 0; m < 4; m++) {
            bf16x8 av = *(const bf16x8*)&Al[(m*16 + l15)*200 + kk*32 + lhi*8];
            acc[m] = __builtin_amdgcn_mfma_f32_16x16x32_bf16(av, bv, acc[m], 0, 0, 0);
        }
    }
    int o = wave*16 + l15;
    float bias = biasl[o];
#pragma unroll
    for (int m = 0; m < 4; m++) {
        int brow = m*16 + lhi*4;
#pragma unroll
        for (int r = 0; r < 4; r++)
            out[(long)(brow + r)*XSTRIDE + n*64 + o] = acc[m][r] + bias;
    }
}

extern "C" void kernel_launch(void* const* d_in, const int* in_sizes, int n_in,
                              void* d_out, int out_size, void* d_ws, size_t ws_size,
                              hipStream_t stream) {
    const float* x     = (const float*)d_in[0];
    const float* nodee = (const float*)d_in[1];
    const float* timee = (const float*)d_in[2];
    const float* wp    = (const float*)d_in[3];
    const float* bp    = (const float*)d_in[4];
    const float* gamma = (const float*)d_in[5];
    const float* beta  = (const float*)d_in[6];
    float* out = (float*)d_out;

    char* ws = (char*)d_ws;
    // layout (bytes)
    float* ne  = (float*)(ws);                         // 131072
    u16* S     = (u16*)(ws + 131072);                  // 8 MB
    u16* Xpt   = (u16*)(ws + 8519680);                 // 16 MB  [4096][2048]
    u16* Y1    = (u16*)(ws + 25296896);                // 16 MB  [2048][4096]
    u16* Y1t   = (u16*)(ws + 42074112);                // 16 MB  [4096][2048]
    u16* Y2    = (u16*)(ws + 58851328);                // 16 MB  [2048][4096]
    u16* Wt    = (u16*)(ws + 75628544);                // 48 MB  [2048][64][192]
    // neb/wpP live in the Y2 region: both fully consumed by the weight GEMM
    // (dispatch 3) before gemm2 (dispatch 7) overwrites Y2. Same stream -> safe.
    u16* neb   = (u16*)(ws + 58851328);                // 128 KB [2048][32]
    u16* wpP   = (u16*)(ws + 58851328 + 131072);       // 768 KB [12288][32]
    if (ws_size < (size_t)125960192) return;           // need ~120.1 MB scratch

    k_ln      <<<8,    256, 0, stream>>>(nodee, timee, gamma, beta, ne, neb);
    k_wperm   <<<48,   256, 0, stream>>>(wp, wpP);
    k_gemm_bt <<<dim3(96,16), 256, 0, stream>>>(neb, wpP, Wt, 2048, 12288, 32);
    k_softmax <<<2048, 256, 0, stream>>>(ne, S);
    k_permute <<<2048, 256, 0, stream>>>(x, Xpt);
    k_gemm_big<<<dim3(16,16), 512, 0, stream>>>(S, Xpt, Y1, Y1t, 2048, 4096, 2048);
    k_gemm_big<<<dim3(16,16), 512, 0, stream>>>(S, Y1t, Y2, (u16*)nullptr, 2048, 4096, 2048);
    k_final   <<<2048, 256, 0, stream>>>(x, Y1, Y2, Wt, ne, bp, out);
}

// Round 9
// 140.618 us; speedup vs baseline: 1.1181x; 1.1181x over previous
//
#include <hip/hip_runtime.h>
#include <stdint.h>

typedef unsigned short u16;
typedef __attribute__((ext_vector_type(8))) short   bf16x8;
typedef __attribute__((ext_vector_type(4))) float   f32x4;
typedef __attribute__((ext_vector_type(4))) u16     u16x4;
typedef __attribute__((ext_vector_type(8))) u16     u16x8;

#define NN 2048      // nodes
#define BB 64        // batch
#define DD 64        // d_in = d_out
#define XSTRIDE (NN*DD)   // per-batch stride in x/out = 131072

__device__ __forceinline__ float bf2f(u16 u) {
    union { unsigned int i; float f; } v; v.i = ((unsigned int)u) << 16; return v.f;
}
__device__ __forceinline__ u16 f2bf(float f) {   // round-to-nearest-even
    union { float f; unsigned int i; } v; v.f = f;
    unsigned int u = v.i;
    return (u16)((u + 0x7fffu + ((u >> 16) & 1u)) >> 16);
}

typedef __attribute__((address_space(3))) unsigned int lds_u32_t;
typedef const __attribute__((address_space(1))) unsigned int g_u32_t;
__device__ __forceinline__ void gload_lds16(const void* g, void* l) {
    __builtin_amdgcn_global_load_lds((g_u32_t*)(uintptr_t)g, (lds_u32_t*)(uintptr_t)l, 16, 0, 0);
}

// ---- 1. LayerNorm over E=16 -> ne [2048][16] f32  +  neb [2048][32] bf16 ----
__global__ __launch_bounds__(256) void k_ln(const float* __restrict__ nodee,
                                            const float* __restrict__ timee,
                                            const float* __restrict__ gamma,
                                            const float* __restrict__ beta,
                                            float* __restrict__ ne,
                                            u16* __restrict__ neb) {
    int n = blockIdx.x * 256 + threadIdx.x;   // 8*256 = 2048
    float v[16]; float mu = 0.f;
    const float4* p = (const float4*)(nodee + (long)n * 16);
#pragma unroll
    for (int i = 0; i < 4; i++) {
        float4 q = p[i];
        v[i*4+0]=q.x; v[i*4+1]=q.y; v[i*4+2]=q.z; v[i*4+3]=q.w;
    }
#pragma unroll
    for (int e = 0; e < 16; e++) { v[e] += timee[e]; mu += v[e]; }
    mu *= (1.f/16.f);
    float var = 0.f;
#pragma unroll
    for (int e = 0; e < 16; e++) { float d = v[e]-mu; var += d*d; }
    var *= (1.f/16.f);
    float rs = rsqrtf(var + 1e-12f);
    float4* o = (float4*)(ne + (long)n * 16);
    u16x8 nb[2];
#pragma unroll
    for (int i = 0; i < 4; i++) {
        float4 q;
        q.x = (v[i*4+0]-mu)*rs*gamma[i*4+0] + beta[i*4+0];
        q.y = (v[i*4+1]-mu)*rs*gamma[i*4+1] + beta[i*4+1];
        q.z = (v[i*4+2]-mu)*rs*gamma[i*4+2] + beta[i*4+2];
        q.w = (v[i*4+3]-mu)*rs*gamma[i*4+3] + beta[i*4+3];
        o[i] = q;
        nb[i>>1][(i&1)*4+0] = f2bf(q.x); nb[i>>1][(i&1)*4+1] = f2bf(q.y);
        nb[i>>1][(i&1)*4+2] = f2bf(q.z); nb[i>>1][(i&1)*4+3] = f2bf(q.w);
    }
    u16x8 z;
#pragma unroll
    for (int j = 0; j < 8; j++) z[j] = 0;
    u16x8* ob = (u16x8*)&neb[(long)n * 32];
    ob[0] = nb[0]; ob[1] = nb[1]; ob[2] = z; ob[3] = z;
}

// ---- 2. wpP[j=o*192+ki][e(pad32)] = bf16(wp[e][ki][o])  [12288][32] ---------
__global__ __launch_bounds__(256) void k_wperm(const float* __restrict__ wp,
                                               u16* __restrict__ wpP) {
    int j = blockIdx.x * 256 + threadIdx.x;   // 48 blocks
    int o = j / 192, ki = j - o * 192;
    int src = ki * 64 + o;
    u16x8 ov[4];
#pragma unroll
    for (int e = 0; e < 16; e++) ov[e>>3][e&7] = f2bf(wp[(long)e*12288 + src]);
#pragma unroll
    for (int e = 0; e < 8; e++) { ov[2][e] = 0; ov[3][e] = 0; }
    u16x8* dst = (u16x8*)&wpP[(long)j * 32];
    dst[0]=ov[0]; dst[1]=ov[1]; dst[2]=ov[2]; dst[3]=ov[3];
}

// ---- 3. S = softmax(ne @ ne^T), 4 rows/block -> bf16 [2048][2048] -----------
__global__ __launch_bounds__(256) void k_softmax(const float* __restrict__ ne,
                                                 u16* __restrict__ S) {
    __shared__ float row[4][2048];
    __shared__ float red[4][4];
    int n0 = blockIdx.x * 4, t = threadIdx.x;   // 512 blocks
    int wave = t >> 6, lane = t & 63;
    f32x4 nev[4][4];
#pragma unroll
    for (int r = 0; r < 4; r++)
#pragma unroll
        for (int i = 0; i < 4; i++) nev[r][i] = *(const f32x4*)&ne[(n0+r)*16 + i*4];
    float lmax[4] = {-1e30f, -1e30f, -1e30f, -1e30f};
    for (int m = t; m < 2048; m += 256) {
        const f32x4* p = (const f32x4*)&ne[m*16];
        f32x4 p0 = p[0], p1 = p[1], p2 = p[2], p3 = p[3];
#pragma unroll
        for (int r = 0; r < 4; r++) {
            f32x4 d4 = nev[r][0]*p0 + nev[r][1]*p1 + nev[r][2]*p2 + nev[r][3]*p3;
            float d = d4[0]+d4[1]+d4[2]+d4[3];
            row[r][m] = d;
            lmax[r] = fmaxf(lmax[r], d);
        }
    }
#pragma unroll
    for (int r = 0; r < 4; r++)
#pragma unroll
        for (int off = 32; off > 0; off >>= 1) lmax[r] = fmaxf(lmax[r], __shfl_xor(lmax[r], off));
    if (lane == 0) {
#pragma unroll
        for (int r = 0; r < 4; r++) red[r][wave] = lmax[r];
    }
    __syncthreads();
    float gmax[4], lsum[4] = {0.f, 0.f, 0.f, 0.f};
#pragma unroll
    for (int r = 0; r < 4; r++)
        gmax[r] = fmaxf(fmaxf(red[r][0], red[r][1]), fmaxf(red[r][2], red[r][3]));
    for (int m = t; m < 2048; m += 256) {
#pragma unroll
        for (int r = 0; r < 4; r++) {
            float ev = __expf(row[r][m] - gmax[r]);
            row[r][m] = ev;
            lsum[r] += ev;
        }
    }
#pragma unroll
    for (int r = 0; r < 4; r++)
#pragma unroll
        for (int off = 32; off > 0; off >>= 1) lsum[r] += __shfl_xor(lsum[r], off);
    __syncthreads();                 // gmax reads of red done
    if (lane == 0) {
#pragma unroll
        for (int r = 0; r < 4; r++) red[r][wave] = lsum[r];
    }
    __syncthreads();
    float inv[4];
#pragma unroll
    for (int r = 0; r < 4; r++)
        inv[r] = 1.f / (red[r][0] + red[r][1] + red[r][2] + red[r][3]);
    for (int m = t; m < 2048; m += 256) {
#pragma unroll
        for (int r = 0; r < 4; r++)
            S[(long)(n0+r)*2048 + m] = f2bf(row[r][m] * inv[r]);
    }
}

// ---- 4. permute: Xpt[j=(b,c)][m] and Xb[m][b*64+c], both bf16 ---------------
__global__ __launch_bounds__(256) void k_permute(const float* __restrict__ x,
                                                 u16* __restrict__ Xpt,
                                                 u16* __restrict__ Xb) {
    __shared__ u16 T[64][72];
    int bid = blockIdx.x;             // 64 b * 32 m-tiles
    int b = bid >> 5, m0 = (bid & 31) * 64;
    int t = threadIdx.x;
#pragma unroll
    for (int it = 0; it < 4; it++) {
        int fi = it*256 + t;
        int row = fi >> 4, c4 = (fi & 15) * 4;   // row = local m
        float4 v = *(const float4*)&x[(long)b*XSTRIDE + (m0+row)*64 + c4];
        T[c4+0][row] = f2bf(v.x); T[c4+1][row] = f2bf(v.y);
        T[c4+2][row] = f2bf(v.z); T[c4+3][row] = f2bf(v.w);
    }
    __syncthreads();
#pragma unroll
    for (int it = 0; it < 2; it++) {
        int ch = it*256 + t;
        int c = ch >> 3, m8 = (ch & 7) * 8;
        u16x8 v = *(const u16x8*)&T[c][m8];
        *(u16x8*)&Xpt[(long)(b*64 + c)*2048 + m0 + m8] = v;
    }
#pragma unroll
    for (int it = 0; it < 4; it++) {
        int wi = it*256 + t;
        int m = wi >> 4, c4 = (wi & 15) * 4;
        u16x4 v;
        v[0] = T[c4+0][m]; v[1] = T[c4+1][m]; v[2] = T[c4+2][m]; v[3] = T[c4+3][m];
        *(u16x4*)&Xb[(long)(m0 + m)*4096 + b*64 + c4] = v;
    }
}

// ---- 5a. small-K GEMM (weight pool): C = A * Bt^T, 128x128 tile, K small ----
__global__ __launch_bounds__(256) void k_gemm_bt(const u16* __restrict__ A,
                                                 const u16* __restrict__ Bt,
                                                 u16* __restrict__ C,
                                                 int M, int Ncols, int K) {
    __shared__ __align__(16) u16 As[128*32];
    __shared__ __align__(16) u16 Bs[128*32];
    const int t = threadIdx.x;
    const int wave = t >> 6, lane = t & 63;
    const int l15 = lane & 15, lhi = lane >> 4;
    const int m0 = blockIdx.y * 128;
    const int n0 = blockIdx.x * 128;
    const int wr = wave >> 1, wc = wave & 1;
    f32x4 acc[4][4] = {};
    const int srow = t >> 2;
    const int sk = (t & 3) * 8;
    const u16* gA = A + (long)(m0 + srow) * K + sk;
    const u16* gB = Bt + (long)(n0 + srow) * K + sk;
    const long half = (long)64 * K;
    u16* lA = As + wave * 512;   // elems; wave-uniform base, HW adds lane*16B
    u16* lB = Bs + wave * 512;
    const int aoff = (wr*64 + l15)*32 + lhi*8;
    const int boff = (wc*64 + l15)*32 + lhi*8;
    for (int k0 = 0; k0 < K; k0 += 32) {
        gload_lds16(gA + k0,        lA);
        gload_lds16(gA + k0 + half, lA + 2048);
        gload_lds16(gB + k0,        lB);
        gload_lds16(gB + k0 + half, lB + 2048);
        __syncthreads();
        bf16x8 af[4], bv[4];
#pragma unroll
        for (int m = 0; m < 4; m++) af[m] = *(const bf16x8*)&As[aoff + m*512];
#pragma unroll
        for (int q = 0; q < 4; q++) bv[q] = *(const bf16x8*)&Bs[boff + q*512];
#pragma unroll
        for (int m = 0; m < 4; m++)
#pragma unroll
            for (int q = 0; q < 4; q++)
                acc[m][q] = __builtin_amdgcn_mfma_f32_16x16x32_bf16(af[m], bv[q], acc[m][q], 0, 0, 0);
        __syncthreads();
    }
#pragma unroll
    for (int m = 0; m < 4; m++) {
        int row = m0 + wr*64 + m*16 + lhi*4;
#pragma unroll
        for (int q = 0; q < 4; q++) {
            int col = n0 + wc*64 + q*16 + l15;
#pragma unroll
            for (int r = 0; r < 4; r++)
                C[(long)(row + r) * Ncols + col] = f2bf(acc[m][q][r]);
        }
    }
}

// ---- 5b. big GEMM: C[M][Ncols] = A[M][K]*Bt[Ncols][K]^T, optional Ct=C^T ----
// R7-proven config (best measured): BM=128, BN=256, BK=64, 512 thr = 8 waves
// (2Mx4N), wave-tile 64x64. Triple-buffered 144KB LDS, 2-tile-ahead prefetch,
// ONE counted vmcnt(6) + ONE barrier per K-tile (T3+T4), XOR-swizzled LDS
// both-sides (T2), setprio (T5), XCD swizzle (T1).
__global__ __launch_bounds__(512, 1) void k_gemm_big(const u16* __restrict__ A,
                                                     const u16* __restrict__ Bt,
                                                     u16* __restrict__ C,
                                                     u16* __restrict__ Ct,
                                                     int M, int Ncols, int K) {
    __shared__ __align__(16) u16 LB[73728];   // 144 KB: A 3x8192 @0, B 3x16384 @24576
    const int t = threadIdx.x;
    const int wave = t >> 6, lane = t & 63;
    const int l15 = lane & 15, lhi = lane >> 4;
    // T1: XCD swizzle (nwg = 256, divisible by 8)
    const int nwg = gridDim.x * gridDim.y;
    const int wgid = blockIdx.y * gridDim.x + blockIdx.x;
    const int swz = (wgid & 7) * (nwg >> 3) + (wgid >> 3);
    const int by = swz / gridDim.x, bx = swz - by * gridDim.x;
    const int m0 = by * 128, n0 = bx * 256;
    const int wr = wave >> 2, wc = wave & 3;   // 2M x 4N wave grid
    const int NT = K >> 6;
    f32x4 acc[4][4] = {};

    // staging: chunk c = pass*512 + t; row = pass*64 + (t>>3), slot = t&7.
    // inverse swizzle: global k8-chunk = slot ^ (row&7); pass*64 == 0 mod 8.
    const int srow = t >> 3;
    const int sswz = ((t & 7) ^ (srow & 7)) * 8;
    const u16* gA0 = A  + (long)(m0 + srow) * K + sswz;
    const u16* gB0 = Bt + (long)(n0 + srow) * K + sswz;
    const long rP = (long)64 * K;   // 64-row advance per staging pass
    const int ldsW = wave * 512;    // wave-uniform dest base (elems); HW adds lane*16B

    int curA = 0,     nxtA = 8192,  tgtA = 16384;
    int curB = 24576, nxtB = 40960, tgtB = 57344;

    // prologue: tile 0 -> cur, tile 1 -> nxt (6 loads per wave per tile)
    gload_lds16(gA0,           &LB[curA + 0*4096 + ldsW]);
    gload_lds16(gA0 + rP,      &LB[curA + 1*4096 + ldsW]);
#pragma unroll
    for (int r = 0; r < 4; r++) gload_lds16(gB0 + r*rP,      &LB[curB + r*4096 + ldsW]);
    gload_lds16(gA0 + 64,      &LB[nxtA + 0*4096 + ldsW]);
    gload_lds16(gA0 + rP + 64, &LB[nxtA + 1*4096 + ldsW]);
#pragma unroll
    for (int r = 0; r < 4; r++) gload_lds16(gB0 + r*rP + 64, &LB[nxtB + r*4096 + ldsW]);
    asm volatile("s_waitcnt vmcnt(6)" ::: "memory");   // tile 0 resident
    __builtin_amdgcn_s_barrier();
    asm volatile("" ::: "memory");

    // read-side addressing: row has 8 slots of 8 elems; logical slot g (=ks*4+lhi)
    // lives at LDS slot g ^ (row&7); m*16 / q*16 don't change row&7.
    const int rsw = l15 & 7;
    const int sw0 = (lhi ^ rsw) * 8;         // kstep 0
    const int sw1 = ((4 + lhi) ^ rsw) * 8;   // kstep 1
    const int abase = (wr*64 + l15) * 64;
    const int bbase = (wc*64 + l15) * 64;

#pragma unroll 1
    for (int tt = 0; tt < NT; tt++) {
        const bool stg = (tt + 2 < NT);
        const long ko2 = (long)((tt + 2) << 6);
        // ---------- phase 0 (kstep 0) ----------
        {
            bf16x8 af[4], bv[4];
#pragma unroll
            for (int m = 0; m < 4; m++) af[m] = *(const bf16x8*)&LB[curA + abase + m*1024 + sw0];
#pragma unroll
            for (int q = 0; q < 4; q++) bv[q] = *(const bf16x8*)&LB[curB + bbase + q*1024 + sw0];
            if (stg) {
                gload_lds16(gA0 + ko2,      &LB[tgtA + 0*4096 + ldsW]);
                gload_lds16(gA0 + rP + ko2, &LB[tgtA + 1*4096 + ldsW]);
                gload_lds16(gB0 + ko2,      &LB[tgtB + 0*4096 + ldsW]);
            }
            __builtin_amdgcn_s_setprio(1);
#pragma unroll
            for (int m = 0; m < 4; m++)
#pragma unroll
                for (int q = 0; q < 4; q++)
                    acc[m][q] = __builtin_amdgcn_mfma_f32_16x16x32_bf16(af[m], bv[q], acc[m][q], 0, 0, 0);
            __builtin_amdgcn_s_setprio(0);
        }
        // ---------- phase 1 (kstep 1) ----------
        {
            bf16x8 af[4], bv[4];
#pragma unroll
            for (int m = 0; m < 4; m++) af[m] = *(const bf16x8*)&LB[curA + abase + m*1024 + sw1];
#pragma unroll
            for (int q = 0; q < 4; q++) bv[q] = *(const bf16x8*)&LB[curB + bbase + q*1024 + sw1];
            if (stg) {
                gload_lds16(gB0 + 1*rP + ko2, &LB[tgtB + 1*4096 + ldsW]);
                gload_lds16(gB0 + 2*rP + ko2, &LB[tgtB + 2*4096 + ldsW]);
                gload_lds16(gB0 + 3*rP + ko2, &LB[tgtB + 3*4096 + ldsW]);
            }
            __builtin_amdgcn_s_setprio(1);
#pragma unroll
            for (int m = 0; m < 4; m++)
#pragma unroll
                for (int q = 0; q < 4; q++)
                    acc[m][q] = __builtin_amdgcn_mfma_f32_16x16x32_bf16(af[m], bv[q], acc[m][q], 0, 0, 0);
            __builtin_amdgcn_s_setprio(0);
        }
        // ---------- end of tile: counted wait + raw barrier ----------
        asm volatile("" ::: "memory");
        if (stg)                asm volatile("s_waitcnt vmcnt(6)" ::: "memory");
        else if (tt + 1 < NT)   asm volatile("s_waitcnt vmcnt(0)" ::: "memory");
        if (tt + 1 < NT) {
            __builtin_amdgcn_s_barrier();
            asm volatile("" ::: "memory");
        }
        int ta = curA; curA = nxtA; nxtA = tgtA; tgtA = ta;
        int tb = curB; curB = nxtB; nxtB = tgtB; tgtB = tb;
    }
    // normal C write
#pragma unroll
    for (int m = 0; m < 4; m++) {
        int row = m0 + wr*64 + m*16 + lhi*4;
#pragma unroll
        for (int q = 0; q < 4; q++) {
            int col = n0 + wc*64 + q*16 + l15;
#pragma unroll
            for (int r = 0; r < 4; r++)
                C[(long)(row + r) * Ncols + col] = f2bf(acc[m][q][r]);
        }
    }
    // optional transposed write via LDS tile (stride 136: conflict-light)
    if (Ct != nullptr) {
        __syncthreads();   // K-loop LDS reads done before reuse
#pragma unroll
        for (int m = 0; m < 4; m++) {
            int rowb = wr*64 + m*16 + lhi*4;
#pragma unroll
            for (int q = 0; q < 4; q++) {
                int col = wc*64 + q*16 + l15;
                u16x4 p;
                p[0]=f2bf(acc[m][q][0]); p[1]=f2bf(acc[m][q][1]);
                p[2]=f2bf(acc[m][q][2]); p[3]=f2bf(acc[m][q][3]);
                *(u16x4*)&LB[col*136 + rowb] = p;
            }
        }
        __syncthreads();
        const int j16 = t >> 4, ch = (t & 15) * 8;
#pragma unroll
        for (int p = 0; p < 8; p++) {
            int j = p*32 + j16;
            u16x8 v = *(const u16x8*)&LB[j*136 + ch];
            *(u16x8*)&Ct[(long)(n0 + j)*M + m0 + ch] = v;
        }
    }
}

// ---- 7. final: out[b][n][o] = sum_ki xg[b][ki]*W_n[ki][o] + bias ------------
// A-operands from bf16 Xb (k=0), Y1 (k=1), 2*Y2-Xb (k=2); W from Wt (L3-hot).
__global__ __launch_bounds__(256) void k_final(const u16* __restrict__ Xb,
                                               const u16* __restrict__ Y1,
                                               const u16* __restrict__ Y2,
                                               const u16* __restrict__ Wt,
                                               const float* __restrict__ ne,
                                               const float* __restrict__ bp,
                                               float* __restrict__ out) {
    __shared__ __align__(16) u16 Al[64*200];
    __shared__ __align__(16) u16 Wl[64*200];
    __shared__ float biasl[64];
    int n = blockIdx.x;
    int t = threadIdx.x;
    int wave = t >> 6, lane = t & 63;
    int l15 = lane & 15, lhi = lane >> 4;
    // W_n^T: global [o][ki] rows of 192 (192%8==0 so 8-chunks never cross rows)
#pragma unroll
    for (int it = 0; it < 6; it++) {
        int ch = it*256 + t;
        int o = ch / 24, kl = (ch % 24) * 8;
        u16x8 v = *(const u16x8*)&Wt[(long)n*12288 + ch*8];
        *(u16x8*)&Wl[o*200 + kl] = v;
    }
    // k=0 (Xb) and k=2 (2*Y2 - Xb), fused: same j-chunks
#pragma unroll
    for (int it = 0; it < 2; it++) {
        int ch = it*256 + t;          // 512 chunks of 8 j; b = j>>6, i = j&63
        int b = ch >> 3, i8 = (ch & 7) * 8;
        u16x8 xv = *(const u16x8*)&Xb[(long)n*4096 + ch*8];
        *(u16x8*)&Al[b*200 + i8] = xv;
        u16x8 yv = *(const u16x8*)&Y2[(long)n*4096 + ch*8];
        u16x8 p;
#pragma unroll
        for (int j = 0; j < 8; j++) p[j] = f2bf(2.f*bf2f(yv[j]) - bf2f(xv[j]));
        *(u16x8*)&Al[b*200 + 128 + i8] = p;
    }
    // k=1 : Y1 row n
#pragma unroll
    for (int it = 0; it < 2; it++) {
        int ch = it*256 + t;
        int b = ch >> 3, i8 = (ch & 7)*8;
        u16x8 v = *(const u16x8*)&Y1[(long)n*4096 + ch*8];
        *(u16x8*)&Al[b*200 + 64 + i8] = v;
    }
    if (t < 64) {
        float s = 0.f;
#pragma unroll
        for (int e = 0; e < 16; e++) s += ne[n*16+e] * bp[e*64 + t];
        biasl[t] = s;
    }
    __syncthreads();
    f32x4 acc[4] = {};
#pragma unroll
    for (int kk = 0; kk < 6; kk++) {
        bf16x8 bv = *(const bf16x8*)&Wl[(wave*16 + l15)*200 + kk*32 + lhi*8];
#pragma unroll
        for (int m = 0; m < 4; m++) {
            bf16x8 av = *(const bf16x8*)&Al[(m*16 + l15)*200 + kk*32 + lhi*8];
            acc[m] = __builtin_amdgcn_mfma_f32_16x16x32_bf16(av, bv, acc[m], 0, 0, 0);
        }
    }
    int o = wave*16 + l15;
    float bias = biasl[o];
#pragma unroll
    for (int m = 0; m < 4; m++) {
        int brow = m*16 + lhi*4;
#pragma unroll
        for (int r = 0; r < 4; r++)
            out[(long)(brow + r)*XSTRIDE + n*64 + o] = acc[m][r] + bias;
    }
}

extern "C" void kernel_launch(void* const* d_in, const int* in_sizes, int n_in,
                              void* d_out, int out_size, void* d_ws, size_t ws_size,
                              hipStream_t stream) {
    const float* x     = (const float*)d_in[0];
    const float* nodee = (const float*)d_in[1];
    const float* timee = (const float*)d_in[2];
    const float* wp    = (const float*)d_in[3];
    const float* bp    = (const float*)d_in[4];
    const float* gamma = (const float*)d_in[5];
    const float* beta  = (const float*)d_in[6];
    float* out = (float*)d_out;

    char* ws = (char*)d_ws;
    // layout (bytes)
    float* ne  = (float*)(ws);                         // 128 KB
    u16* S     = (u16*)(ws + 131072);                  // 8 MB
    u16* Xpt   = (u16*)(ws + 8519680);                 // 16 MB  [4096][2048]
    u16* Y1    = (u16*)(ws + 25296896);                // 16 MB  [2048][4096]
    u16* Y1t   = (u16*)(ws + 42074112);                // 16 MB  [4096][2048]
    u16* Y2    = (u16*)(ws + 58851328);                // 16 MB  [2048][4096]
    u16* Wt    = (u16*)(ws + 75628544);                // 48 MB  [2048][64][192]
    u16* neb   = (u16*)(ws + 125960192);               // 128 KB [2048][32]
    u16* wpP   = (u16*)(ws + 126091264);               // 768 KB [12288][32]
    u16* Xb    = (u16*)(ws + 127664128);               // 16 MB  [2048][4096]
    if (ws_size < (size_t)144441344) return;           // need ~137.8 MB scratch

    k_ln      <<<8,    256, 0, stream>>>(nodee, timee, gamma, beta, ne, neb);
    k_wperm   <<<48,   256, 0, stream>>>(wp, wpP);
    k_softmax <<<512,  256, 0, stream>>>(ne, S);
    k_permute <<<2048, 256, 0, stream>>>(x, Xpt, Xb);
    k_gemm_big<<<dim3(16,16), 512, 0, stream>>>(S, Xpt, Y1, Y1t, 2048, 4096, 2048);
    k_gemm_big<<<dim3(16,16), 512, 0, stream>>>(S, Y1t, Y2, (u16*)nullptr, 2048, 4096, 2048);
    // weight GEMM last so Wt (48 MB) is L3-resident when k_final reads it
    k_gemm_bt <<<dim3(96,16), 256, 0, stream>>>(neb, wpP, Wt, 2048, 12288, 32);
    k_final   <<<2048, 256, 0, stream>>>(Xb, Y1, Y2, Wt, ne, bp, out);
}

// Round 10
// 130.802 us; speedup vs baseline: 1.2020x; 1.0750x over previous
//
#include <hip/hip_runtime.h>
#include <stdint.h>

typedef unsigned short u16;
typedef __attribute__((ext_vector_type(8))) short   bf16x8;
typedef __attribute__((ext_vector_type(4))) float   f32x4;
typedef __attribute__((ext_vector_type(4))) u16     u16x4;
typedef __attribute__((ext_vector_type(8))) u16     u16x8;

#define NN 2048      // nodes
#define BB 64        // batch
#define DD 64        // d_in = d_out
#define XSTRIDE (NN*DD)   // per-batch stride in x/out = 131072

__device__ __forceinline__ float bf2f(u16 u) {
    union { unsigned int i; float f; } v; v.i = ((unsigned int)u) << 16; return v.f;
}
__device__ __forceinline__ u16 f2bf(float f) {   // round-to-nearest-even
    union { float f; unsigned int i; } v; v.f = f;
    unsigned int u = v.i;
    return (u16)((u + 0x7fffu + ((u >> 16) & 1u)) >> 16);
}

typedef __attribute__((address_space(3))) unsigned int lds_u32_t;
typedef const __attribute__((address_space(1))) unsigned int g_u32_t;
__device__ __forceinline__ void gload_lds16(const void* g, void* l) {
    __builtin_amdgcn_global_load_lds((g_u32_t*)(uintptr_t)g, (lds_u32_t*)(uintptr_t)l, 16, 0, 0);
}

// ---- 1. fused prep: blocks 0-7 LayerNorm -> ne f32 + neb bf16[2048][32];
//         blocks 8-55 wperm -> wpP[j=o*192+ki][e pad32] bf16 ------------------
__global__ __launch_bounds__(256) void k_prep(const float* __restrict__ nodee,
                                              const float* __restrict__ timee,
                                              const float* __restrict__ gamma,
                                              const float* __restrict__ beta,
                                              const float* __restrict__ wp,
                                              float* __restrict__ ne,
                                              u16* __restrict__ neb,
                                              u16* __restrict__ wpP) {
    int t = threadIdx.x;
    if (blockIdx.x < 8) {
        int n = blockIdx.x * 256 + t;
        float v[16]; float mu = 0.f;
        const float4* p = (const float4*)(nodee + (long)n * 16);
#pragma unroll
        for (int i = 0; i < 4; i++) {
            float4 q = p[i];
            v[i*4+0]=q.x; v[i*4+1]=q.y; v[i*4+2]=q.z; v[i*4+3]=q.w;
        }
#pragma unroll
        for (int e = 0; e < 16; e++) { v[e] += timee[e]; mu += v[e]; }
        mu *= (1.f/16.f);
        float var = 0.f;
#pragma unroll
        for (int e = 0; e < 16; e++) { float d = v[e]-mu; var += d*d; }
        var *= (1.f/16.f);
        float rs = rsqrtf(var + 1e-12f);
        float4* o = (float4*)(ne + (long)n * 16);
        u16x8 nb[2];
#pragma unroll
        for (int i = 0; i < 4; i++) {
            float4 q;
            q.x = (v[i*4+0]-mu)*rs*gamma[i*4+0] + beta[i*4+0];
            q.y = (v[i*4+1]-mu)*rs*gamma[i*4+1] + beta[i*4+1];
            q.z = (v[i*4+2]-mu)*rs*gamma[i*4+2] + beta[i*4+2];
            q.w = (v[i*4+3]-mu)*rs*gamma[i*4+3] + beta[i*4+3];
            o[i] = q;
            nb[i>>1][(i&1)*4+0] = f2bf(q.x); nb[i>>1][(i&1)*4+1] = f2bf(q.y);
            nb[i>>1][(i&1)*4+2] = f2bf(q.z); nb[i>>1][(i&1)*4+3] = f2bf(q.w);
        }
        u16x8 z;
#pragma unroll
        for (int j = 0; j < 8; j++) z[j] = 0;
        u16x8* ob = (u16x8*)&neb[(long)n * 32];
        ob[0] = nb[0]; ob[1] = nb[1]; ob[2] = z; ob[3] = z;
    } else {
        int j = (blockIdx.x - 8) * 256 + t;
        int o = j / 192, ki = j - o * 192;
        int src = ki * 64 + o;
        u16x8 ov[4];
#pragma unroll
        for (int e = 0; e < 16; e++) ov[e>>3][e&7] = f2bf(wp[(long)e*12288 + src]);
#pragma unroll
        for (int e = 0; e < 8; e++) { ov[2][e] = 0; ov[3][e] = 0; }
        u16x8* dst = (u16x8*)&wpP[(long)j * 32];
        dst[0]=ov[0]; dst[1]=ov[1]; dst[2]=ov[2]; dst[3]=ov[3];
    }
}

// ---- 2. fused softmax+permute: blocks 0-511 softmax (4 rows each) -> S bf16;
//         blocks 512-2559 permute x -> Xpt[j][m] and Xb[m][j], bf16 -----------
__global__ __launch_bounds__(256) void k_smperm(const float* __restrict__ ne,
                                                u16* __restrict__ S,
                                                const float* __restrict__ x,
                                                u16* __restrict__ Xpt,
                                                u16* __restrict__ Xb) {
    __shared__ __align__(16) char SM[32896];   // union: row[4][2048]+red | T[64][72]
    int t = threadIdx.x;
    if (blockIdx.x < 512) {
        float (*row)[2048] = (float (*)[2048])SM;
        float (*red)[4]    = (float (*)[4])(SM + 32768);
        int n0 = blockIdx.x * 4;
        int wave = t >> 6, lane = t & 63;
        f32x4 nev[4][4];
#pragma unroll
        for (int r = 0; r < 4; r++)
#pragma unroll
            for (int i = 0; i < 4; i++) nev[r][i] = *(const f32x4*)&ne[(n0+r)*16 + i*4];
        float lmax[4] = {-1e30f, -1e30f, -1e30f, -1e30f};
        for (int m = t; m < 2048; m += 256) {
            const f32x4* p = (const f32x4*)&ne[m*16];
            f32x4 p0 = p[0], p1 = p[1], p2 = p[2], p3 = p[3];
#pragma unroll
            for (int r = 0; r < 4; r++) {
                f32x4 d4 = nev[r][0]*p0 + nev[r][1]*p1 + nev[r][2]*p2 + nev[r][3]*p3;
                float d = d4[0]+d4[1]+d4[2]+d4[3];
                row[r][m] = d;
                lmax[r] = fmaxf(lmax[r], d);
            }
        }
#pragma unroll
        for (int r = 0; r < 4; r++)
#pragma unroll
            for (int off = 32; off > 0; off >>= 1) lmax[r] = fmaxf(lmax[r], __shfl_xor(lmax[r], off));
        if (lane == 0) {
#pragma unroll
            for (int r = 0; r < 4; r++) red[r][wave] = lmax[r];
        }
        __syncthreads();
        float gmax[4], lsum[4] = {0.f, 0.f, 0.f, 0.f};
#pragma unroll
        for (int r = 0; r < 4; r++)
            gmax[r] = fmaxf(fmaxf(red[r][0], red[r][1]), fmaxf(red[r][2], red[r][3]));
        for (int m = t; m < 2048; m += 256) {
#pragma unroll
            for (int r = 0; r < 4; r++) {
                float ev = __expf(row[r][m] - gmax[r]);
                row[r][m] = ev;
                lsum[r] += ev;
            }
        }
#pragma unroll
        for (int r = 0; r < 4; r++)
#pragma unroll
            for (int off = 32; off > 0; off >>= 1) lsum[r] += __shfl_xor(lsum[r], off);
        __syncthreads();                 // gmax reads of red done
        if (lane == 0) {
#pragma unroll
            for (int r = 0; r < 4; r++) red[r][wave] = lsum[r];
        }
        __syncthreads();
        float inv[4];
#pragma unroll
        for (int r = 0; r < 4; r++)
            inv[r] = 1.f / (red[r][0] + red[r][1] + red[r][2] + red[r][3]);
        for (int m = t; m < 2048; m += 256) {
#pragma unroll
            for (int r = 0; r < 4; r++)
                S[(long)(n0+r)*2048 + m] = f2bf(row[r][m] * inv[r]);
        }
    } else {
        u16 (*T)[72] = (u16 (*)[72])SM;
        int bid = blockIdx.x - 512;       // 64 b * 32 m-tiles
        int b = bid >> 5, m0 = (bid & 31) * 64;
#pragma unroll
        for (int it = 0; it < 4; it++) {
            int fi = it*256 + t;
            int rw = fi >> 4, c4 = (fi & 15) * 4;   // rw = local m
            float4 v = *(const float4*)&x[(long)b*XSTRIDE + (m0+rw)*64 + c4];
            T[c4+0][rw] = f2bf(v.x); T[c4+1][rw] = f2bf(v.y);
            T[c4+2][rw] = f2bf(v.z); T[c4+3][rw] = f2bf(v.w);
        }
        __syncthreads();
#pragma unroll
        for (int it = 0; it < 2; it++) {
            int ch = it*256 + t;
            int c = ch >> 3, m8 = (ch & 7) * 8;
            u16x8 v = *(const u16x8*)&T[c][m8];
            *(u16x8*)&Xpt[(long)(b*64 + c)*2048 + m0 + m8] = v;
        }
#pragma unroll
        for (int it = 0; it < 4; it++) {
            int wi = it*256 + t;
            int m = wi >> 4, c4 = (wi & 15) * 4;
            u16x4 v;
            v[0] = T[c4+0][m]; v[1] = T[c4+1][m]; v[2] = T[c4+2][m]; v[3] = T[c4+3][m];
            *(u16x4*)&Xb[(long)(m0 + m)*4096 + b*64 + c4] = v;
        }
    }
}

// ---- 5a. small-K GEMM (weight pool): C = A * Bt^T, 128x128 tile, K small ----
__global__ __launch_bounds__(256) void k_gemm_bt(const u16* __restrict__ A,
                                                 const u16* __restrict__ Bt,
                                                 u16* __restrict__ C,
                                                 int M, int Ncols, int K) {
    __shared__ __align__(16) u16 As[128*32];
    __shared__ __align__(16) u16 Bs[128*32];
    const int t = threadIdx.x;
    const int wave = t >> 6, lane = t & 63;
    const int l15 = lane & 15, lhi = lane >> 4;
    const int m0 = blockIdx.y * 128;
    const int n0 = blockIdx.x * 128;
    const int wr = wave >> 1, wc = wave & 1;
    f32x4 acc[4][4] = {};
    const int srow = t >> 2;
    const int sk = (t & 3) * 8;
    const u16* gA = A + (long)(m0 + srow) * K + sk;
    const u16* gB = Bt + (long)(n0 + srow) * K + sk;
    const long half = (long)64 * K;
    u16* lA = As + wave * 512;   // elems; wave-uniform base, HW adds lane*16B
    u16* lB = Bs + wave * 512;
    const int aoff = (wr*64 + l15)*32 + lhi*8;
    const int boff = (wc*64 + l15)*32 + lhi*8;
    for (int k0 = 0; k0 < K; k0 += 32) {
        gload_lds16(gA + k0,        lA);
        gload_lds16(gA + k0 + half, lA + 2048);
        gload_lds16(gB + k0,        lB);
        gload_lds16(gB + k0 + half, lB + 2048);
        __syncthreads();
        bf16x8 af[4], bv[4];
#pragma unroll
        for (int m = 0; m < 4; m++) af[m] = *(const bf16x8*)&As[aoff + m*512];
#pragma unroll
        for (int q = 0; q < 4; q++) bv[q] = *(const bf16x8*)&Bs[boff + q*512];
#pragma unroll
        for (int m = 0; m < 4; m++)
#pragma unroll
            for (int q = 0; q < 4; q++)
                acc[m][q] = __builtin_amdgcn_mfma_f32_16x16x32_bf16(af[m], bv[q], acc[m][q], 0, 0, 0);
        __syncthreads();
    }
#pragma unroll
    for (int m = 0; m < 4; m++) {
        int row = m0 + wr*64 + m*16 + lhi*4;
#pragma unroll
        for (int q = 0; q < 4; q++) {
            int col = n0 + wc*64 + q*16 + l15;
#pragma unroll
            for (int r = 0; r < 4; r++)
                C[(long)(row + r) * Ncols + col] = f2bf(acc[m][q][r]);
        }
    }
}

// ---- 5b. big GEMM: C[M][Ncols] = A[M][K]*Bt[Ncols][K]^T, optional Ct=C^T ----
// R7-proven config (best measured): BM=128, BN=256, BK=64, 512 thr = 8 waves
// (2Mx4N), wave-tile 64x64. Triple-buffered 144KB LDS, 2-tile-ahead prefetch,
// ONE counted vmcnt(6) + ONE barrier per K-tile (T3+T4), XOR-swizzled LDS
// both-sides (T2), setprio (T5), XCD swizzle (T1).
__global__ __launch_bounds__(512, 1) void k_gemm_big(const u16* __restrict__ A,
                                                     const u16* __restrict__ Bt,
                                                     u16* __restrict__ C,
                                                     u16* __restrict__ Ct,
                                                     int M, int Ncols, int K) {
    __shared__ __align__(16) u16 LB[73728];   // 144 KB: A 3x8192 @0, B 3x16384 @24576
    const int t = threadIdx.x;
    const int wave = t >> 6, lane = t & 63;
    const int l15 = lane & 15, lhi = lane >> 4;
    // T1: XCD swizzle (nwg = 256, divisible by 8)
    const int nwg = gridDim.x * gridDim.y;
    const int wgid = blockIdx.y * gridDim.x + blockIdx.x;
    const int swz = (wgid & 7) * (nwg >> 3) + (wgid >> 3);
    const int by = swz / gridDim.x, bx = swz - by * gridDim.x;
    const int m0 = by * 128, n0 = bx * 256;
    const int wr = wave >> 2, wc = wave & 3;   // 2M x 4N wave grid
    const int NT = K >> 6;
    f32x4 acc[4][4] = {};

    // staging: chunk c = pass*512 + t; row = pass*64 + (t>>3), slot = t&7.
    // inverse swizzle: global k8-chunk = slot ^ (row&7); pass*64 == 0 mod 8.
    const int srow = t >> 3;
    const int sswz = ((t & 7) ^ (srow & 7)) * 8;
    const u16* gA0 = A  + (long)(m0 + srow) * K + sswz;
    const u16* gB0 = Bt + (long)(n0 + srow) * K + sswz;
    const long rP = (long)64 * K;   // 64-row advance per staging pass
    const int ldsW = wave * 512;    // wave-uniform dest base (elems); HW adds lane*16B

    int curA = 0,     nxtA = 8192,  tgtA = 16384;
    int curB = 24576, nxtB = 40960, tgtB = 57344;

    // prologue: tile 0 -> cur, tile 1 -> nxt (6 loads per wave per tile)
    gload_lds16(gA0,           &LB[curA + 0*4096 + ldsW]);
    gload_lds16(gA0 + rP,      &LB[curA + 1*4096 + ldsW]);
#pragma unroll
    for (int r = 0; r < 4; r++) gload_lds16(gB0 + r*rP,      &LB[curB + r*4096 + ldsW]);
    gload_lds16(gA0 + 64,      &LB[nxtA + 0*4096 + ldsW]);
    gload_lds16(gA0 + rP + 64, &LB[nxtA + 1*4096 + ldsW]);
#pragma unroll
    for (int r = 0; r < 4; r++) gload_lds16(gB0 + r*rP + 64, &LB[nxtB + r*4096 + ldsW]);
    asm volatile("s_waitcnt vmcnt(6)" ::: "memory");   // tile 0 resident
    __builtin_amdgcn_s_barrier();
    asm volatile("" ::: "memory");

    // read-side addressing: row has 8 slots of 8 elems; logical slot g (=ks*4+lhi)
    // lives at LDS slot g ^ (row&7); m*16 / q*16 don't change row&7.
    const int rsw = l15 & 7;
    const int sw0 = (lhi ^ rsw) * 8;         // kstep 0
    const int sw1 = ((4 + lhi) ^ rsw) * 8;   // kstep 1
    const int abase = (wr*64 + l15) * 64;
    const int bbase = (wc*64 + l15) * 64;

#pragma unroll 1
    for (int tt = 0; tt < NT; tt++) {
        const bool stg = (tt + 2 < NT);
        const long ko2 = (long)((tt + 2) << 6);
        // ---------- phase 0 (kstep 0) ----------
        {
            bf16x8 af[4], bv[4];
#pragma unroll
            for (int m = 0; m < 4; m++) af[m] = *(const bf16x8*)&LB[curA + abase + m*1024 + sw0];
#pragma unroll
            for (int q = 0; q < 4; q++) bv[q] = *(const bf16x8*)&LB[curB + bbase + q*1024 + sw0];
            if (stg) {
                gload_lds16(gA0 + ko2,      &LB[tgtA + 0*4096 + ldsW]);
                gload_lds16(gA0 + rP + ko2, &LB[tgtA + 1*4096 + ldsW]);
                gload_lds16(gB0 + ko2,      &LB[tgtB + 0*4096 + ldsW]);
            }
            __builtin_amdgcn_s_setprio(1);
#pragma unroll
            for (int m = 0; m < 4; m++)
#pragma unroll
                for (int q = 0; q < 4; q++)
                    acc[m][q] = __builtin_amdgcn_mfma_f32_16x16x32_bf16(af[m], bv[q], acc[m][q], 0, 0, 0);
            __builtin_amdgcn_s_setprio(0);
        }
        // ---------- phase 1 (kstep 1) ----------
        {
            bf16x8 af[4], bv[4];
#pragma unroll
            for (int m = 0; m < 4; m++) af[m] = *(const bf16x8*)&LB[curA + abase + m*1024 + sw1];
#pragma unroll
            for (int q = 0; q < 4; q++) bv[q] = *(const bf16x8*)&LB[curB + bbase + q*1024 + sw1];
            if (stg) {
                gload_lds16(gB0 + 1*rP + ko2, &LB[tgtB + 1*4096 + ldsW]);
                gload_lds16(gB0 + 2*rP + ko2, &LB[tgtB + 2*4096 + ldsW]);
                gload_lds16(gB0 + 3*rP + ko2, &LB[tgtB + 3*4096 + ldsW]);
            }
            __builtin_amdgcn_s_setprio(1);
#pragma unroll
            for (int m = 0; m < 4; m++)
#pragma unroll
                for (int q = 0; q < 4; q++)
                    acc[m][q] = __builtin_amdgcn_mfma_f32_16x16x32_bf16(af[m], bv[q], acc[m][q], 0, 0, 0);
            __builtin_amdgcn_s_setprio(0);
        }
        // ---------- end of tile: counted wait + raw barrier ----------
        asm volatile("" ::: "memory");
        if (stg)                asm volatile("s_waitcnt vmcnt(6)" ::: "memory");
        else if (tt + 1 < NT)   asm volatile("s_waitcnt vmcnt(0)" ::: "memory");
        if (tt + 1 < NT) {
            __builtin_amdgcn_s_barrier();
            asm volatile("" ::: "memory");
        }
        int ta = curA; curA = nxtA; nxtA = tgtA; tgtA = ta;
        int tb = curB; curB = nxtB; nxtB = tgtB; tgtB = tb;
    }
    // normal C write
#pragma unroll
    for (int m = 0; m < 4; m++) {
        int row = m0 + wr*64 + m*16 + lhi*4;
#pragma unroll
        for (int q = 0; q < 4; q++) {
            int col = n0 + wc*64 + q*16 + l15;
#pragma unroll
            for (int r = 0; r < 4; r++)
                C[(long)(row + r) * Ncols + col] = f2bf(acc[m][q][r]);
        }
    }
    // optional transposed write via LDS tile (stride 136: conflict-light)
    if (Ct != nullptr) {
        __syncthreads();   // K-loop LDS reads done before reuse
#pragma unroll
        for (int m = 0; m < 4; m++) {
            int rowb = wr*64 + m*16 + lhi*4;
#pragma unroll
            for (int q = 0; q < 4; q++) {
                int col = wc*64 + q*16 + l15;
                u16x4 p;
                p[0]=f2bf(acc[m][q][0]); p[1]=f2bf(acc[m][q][1]);
                p[2]=f2bf(acc[m][q][2]); p[3]=f2bf(acc[m][q][3]);
                *(u16x4*)&LB[col*136 + rowb] = p;
            }
        }
        __syncthreads();
        const int j16 = t >> 4, ch = (t & 15) * 8;
#pragma unroll
        for (int p = 0; p < 8; p++) {
            int j = p*32 + j16;
            u16x8 v = *(const u16x8*)&LB[j*136 + ch];
            *(u16x8*)&Ct[(long)(n0 + j)*M + m0 + ch] = v;
        }
    }
}

// ---- 7. final: out[b][n][o] = sum_ki xg[b][ki]*W_n[ki][o] + bias ------------
// A-operands from bf16 Xb (k=0), Y1 (k=1), 2*Y2-Xb (k=2); W from Wt (L3-hot).
__global__ __launch_bounds__(256) void k_final(const u16* __restrict__ Xb,
                                               const u16* __restrict__ Y1,
                                               const u16* __restrict__ Y2,
                                               const u16* __restrict__ Wt,
                                               const float* __restrict__ ne,
                                               const float* __restrict__ bp,
                                               float* __restrict__ out) {
    __shared__ __align__(16) u16 Al[64*200];
    __shared__ __align__(16) u16 Wl[64*200];
    __shared__ float biasl[64];
    int n = blockIdx.x;
    int t = threadIdx.x;
    int wave = t >> 6, lane = t & 63;
    int l15 = lane & 15, lhi = lane >> 4;
    // W_n^T: global [o][ki] rows of 192 (192%8==0 so 8-chunks never cross rows)
#pragma unroll
    for (int it = 0; it < 6; it++) {
        int ch = it*256 + t;
        int o = ch / 24, kl = (ch % 24) * 8;
        u16x8 v = *(const u16x8*)&Wt[(long)n*12288 + ch*8];
        *(u16x8*)&Wl[o*200 + kl] = v;
    }
    // k=0 (Xb) and k=2 (2*Y2 - Xb), fused: same j-chunks
#pragma unroll
    for (int it = 0; it < 2; it++) {
        int ch = it*256 + t;          // 512 chunks of 8 j; b = j>>6, i = j&63
        int b = ch >> 3, i8 = (ch & 7) * 8;
        u16x8 xv = *(const u16x8*)&Xb[(long)n*4096 + ch*8];
        *(u16x8*)&Al[b*200 + i8] = xv;
        u16x8 yv = *(const u16x8*)&Y2[(long)n*4096 + ch*8];
        u16x8 p;
#pragma unroll
        for (int j = 0; j < 8; j++) p[j] = f2bf(2.f*bf2f(yv[j]) - bf2f(xv[j]));
        *(u16x8*)&Al[b*200 + 128 + i8] = p;
    }
    // k=1 : Y1 row n
#pragma unroll
    for (int it = 0; it < 2; it++) {
        int ch = it*256 + t;
        int b = ch >> 3, i8 = (ch & 7)*8;
        u16x8 v = *(const u16x8*)&Y1[(long)n*4096 + ch*8];
        *(u16x8*)&Al[b*200 + 64 + i8] = v;
    }
    if (t < 64) {
        float s = 0.f;
#pragma unroll
        for (int e = 0; e < 16; e++) s += ne[n*16+e] * bp[e*64 + t];
        biasl[t] = s;
    }
    __syncthreads();
    f32x4 acc[4] = {};
#pragma unroll
    for (int kk = 0; kk < 6; kk++) {
        bf16x8 bv = *(const bf16x8*)&Wl[(wave*16 + l15)*200 + kk*32 + lhi*8];
#pragma unroll
        for (int m = 0; m < 4; m++) {
            bf16x8 av = *(const bf16x8*)&Al[(m*16 + l15)*200 + kk*32 + lhi*8];
            acc[m] = __builtin_amdgcn_mfma_f32_16x16x32_bf16(av, bv, acc[m], 0, 0, 0);
        }
    }
    int o = wave*16 + l15;
    float bias = biasl[o];
#pragma unroll
    for (int m = 0; m < 4; m++) {
        int brow = m*16 + lhi*4;
#pragma unroll
        for (int r = 0; r < 4; r++)
            out[(long)(brow + r)*XSTRIDE + n*64 + o] = acc[m][r] + bias;
    }
}

extern "C" void kernel_launch(void* const* d_in, const int* in_sizes, int n_in,
                              void* d_out, int out_size, void* d_ws, size_t ws_size,
                              hipStream_t stream) {
    const float* x     = (const float*)d_in[0];
    const float* nodee = (const float*)d_in[1];
    const float* timee = (const float*)d_in[2];
    const float* wp    = (const float*)d_in[3];
    const float* bp    = (const float*)d_in[4];
    const float* gamma = (const float*)d_in[5];
    const float* beta  = (const float*)d_in[6];
    float* out = (float*)d_out;

    char* ws = (char*)d_ws;
    // layout (bytes)
    float* ne  = (float*)(ws);                         // 128 KB
    u16* S     = (u16*)(ws + 131072);                  // 8 MB
    u16* Xpt   = (u16*)(ws + 8519680);                 // 16 MB  [4096][2048]
    u16* Y1    = (u16*)(ws + 25296896);                // 16 MB  [2048][4096]
    u16* Y1t   = (u16*)(ws + 42074112);                // 16 MB  [4096][2048]
    u16* Y2    = (u16*)(ws + 58851328);                // 16 MB  [2048][4096]
    u16* Wt    = (u16*)(ws + 75628544);                // 48 MB  [2048][64][192]
    u16* neb   = (u16*)(ws + 125960192);               // 128 KB [2048][32]
    u16* wpP   = (u16*)(ws + 126091264);               // 768 KB [12288][32]
    u16* Xb    = (u16*)(ws + 127664128);               // 16 MB  [2048][4096]
    if (ws_size < (size_t)144441344) return;           // need ~137.8 MB scratch

    k_prep    <<<56,   256, 0, stream>>>(nodee, timee, gamma, beta, wp, ne, neb, wpP);
    k_smperm  <<<2560, 256, 0, stream>>>(ne, S, x, Xpt, Xb);
    k_gemm_big<<<dim3(16,16), 512, 0, stream>>>(S, Xpt, Y1, Y1t, 2048, 4096, 2048);
    k_gemm_big<<<dim3(16,16), 512, 0, stream>>>(S, Y1t, Y2, (u16*)nullptr, 2048, 4096, 2048);
    // weight GEMM last so Wt (48 MB) is L3-resident when k_final reads it
    k_gemm_bt <<<dim3(96,16), 256, 0, stream>>>(neb, wpP, Wt, 2048, 12288, 32);
    k_final   <<<2048, 256, 0, stream>>>(Xb, Y1, Y2, Wt, ne, bp, out);
}